// Round 6
// baseline (205.048 us; speedup 1.0000x reference)
//
#include <hip/hip_runtime.h>
#include <hip/hip_fp16.h>

#define B_ROWS 2048
#define C_COLS 65536
#define D_DIM  256
#define N_NEG  50
#define NTILES (C_COLS / 128)   // 512 column tiles

typedef __attribute__((ext_vector_type(8))) short short8;
typedef __attribute__((ext_vector_type(16))) float floatx16;

__device__ __forceinline__ ushort f2bf(float f) {
  unsigned u = __float_as_uint(f);
  unsigned r = (u + 0x7FFFu + ((u >> 16) & 1u)) >> 16;  // RNE
  return (ushort)r;
}

// ---------------- fused fp32 -> bf16 convert for f AND centers, K-block XOR swizzle ----
// Row layout: 256 halves = 4 ktiles x 8 kblks x 8 halves; kblk stored at (kblk ^ (row&7)).
__global__ void cvt_both(const float* __restrict__ f, const float* __restrict__ cen,
                         ushort* __restrict__ fb, ushort* __restrict__ cb, int doCen) {
  int i = blockIdx.x * blockDim.x + threadIdx.x;   // grid exact: (2048+65536)*32 threads
  int row = i >> 5;
  int ka = i & 31, ktile = ka >> 3, kb = ka & 7;
  const float* src; ushort* dst; int r;
  if (row < B_ROWS) { src = f; dst = fb; r = row; }
  else { if (!doCen) return; src = cen; dst = cb; r = row - B_ROWS; }
  const float4* s = (const float4*)(src + (size_t)r * D_DIM + ka * 8);
  float4 a = s[0], b = s[1];
  ushort4 o0, o1;
  o0.x = f2bf(a.x); o0.y = f2bf(a.y); o0.z = f2bf(a.z); o0.w = f2bf(a.w);
  o1.x = f2bf(b.x); o1.y = f2bf(b.y); o1.z = f2bf(b.z); o1.w = f2bf(b.w);
  ushort* d = dst + (size_t)r * D_DIM + ktile * 64 + ((kb ^ (r & 7)) << 3);
  ((ushort4*)d)[0] = o0;
  ((ushort4*)d)[1] = o1;
}

__device__ __forceinline__ void async16(const void* g, void* l) {
  __builtin_amdgcn_global_load_lds((const __attribute__((address_space(1))) void*)g,
                                   (__attribute__((address_space(3))) void*)l,
                                   16, 0, 0);
}

// ---------------- fused GEMM (32x32x16, D[n][m]) + register-space 16:1 group-max ----------------
// grid (16 slabs, 512 tiles), tile-major for cb L2 reuse.
// cand[row][tile][g] = max over cols [tile*128+g*16, +16) with label col masked.
template <bool PREB>
__global__ __launch_bounds__(256, 4)
void gemm_reduce(const ushort* __restrict__ fb,
                 const ushort* __restrict__ cb,
                 const float* __restrict__ cen,
                 const int* __restrict__ label,
                 float* __restrict__ cand) {
  __shared__ __align__(16) ushort Cs[128 * 64];   // centers tile (swizzled kblks)
  __shared__ __align__(16) ushort Fs[128 * 64];   // f tile
  __shared__ int labLDS[128];

  const int tid = threadIdx.x, wave = tid >> 6, lane = tid & 63;
  const int ml = lane & 31, h = lane >> 5;
  const int m0 = blockIdx.x * 128, n0 = blockIdx.y * 128;
  const int bxTile = blockIdx.y;
  if (tid < 128) labLDS[tid] = label[m0 + tid];

  floatx16 acc[2][2] = {};              // [i: n-block 32][j: m-block 32]
  const int wn = (wave >> 1) * 64, wm = (wave & 1) * 64;

  for (int kt = 0; kt < D_DIM / 64; ++kt) {
#pragma unroll
    for (int r = 0; r < 4; ++r) {
      int idx = r * 2048 + wave * 512 + lane * 8;
      int row = idx >> 6, kk = idx & 63;
      async16(fb + (size_t)(m0 + row) * D_DIM + kt * 64 + kk, Fs + r * 2048 + wave * 512);
      if (PREB)
        async16(cb + (size_t)(n0 + row) * D_DIM + kt * 64 + kk, Cs + r * 2048 + wave * 512);
    }
    if (!PREB) {
#pragma unroll
      for (int g = 0; g < 4; ++g) {
        int e = (tid + g * 256) * 8;
        int row = e >> 6, kblk = (e >> 3) & 7;
        const float* gp = cen + (size_t)(n0 + row) * D_DIM + kt * 64 + kblk * 8;
        float4 fa = *(const float4*)gp;
        float4 fbv = *(const float4*)(gp + 4);
        uint4 o;
        o.x = (uint)f2bf(fa.x)  | ((uint)f2bf(fa.y)  << 16);
        o.y = (uint)f2bf(fa.z)  | ((uint)f2bf(fa.w)  << 16);
        o.z = (uint)f2bf(fbv.x) | ((uint)f2bf(fbv.y) << 16);
        o.w = (uint)f2bf(fbv.z) | ((uint)f2bf(fbv.w) << 16);
        *(uint4*)(Cs + (row << 6) + ((kblk ^ (row & 7)) << 3)) = o;
      }
    }
    __syncthreads();

#pragma unroll
    for (int ks = 0; ks < 4; ++ks) {              // K16 steps within BK=64
      const int swz = ((2 * ks + h) ^ (ml & 7)) << 3;
      short8 a[2], b[2];
#pragma unroll
      for (int i = 0; i < 2; ++i) {
        a[i] = *(const short8*)(Cs + ((wn + i * 32 + ml) << 6) + swz);
        b[i] = *(const short8*)(Fs + ((wm + i * 32 + ml) << 6) + swz);
      }
      acc[0][0] = __builtin_amdgcn_mfma_f32_32x32x16_bf16(a[0], b[0], acc[0][0], 0, 0, 0);
      acc[0][1] = __builtin_amdgcn_mfma_f32_32x32x16_bf16(a[0], b[1], acc[0][1], 0, 0, 0);
      acc[1][0] = __builtin_amdgcn_mfma_f32_32x32x16_bf16(a[1], b[0], acc[1][0], 0, 0, 0);
      acc[1][1] = __builtin_amdgcn_mfma_f32_32x32x16_bf16(a[1], b[1], acc[1][1], 0, 0, 0);
    }
    __syncthreads();
  }

  // ---- register-space epilogue ----
  // C/D: m = wm + j*32 + (lane&31); n = n0 + wn + i*32 + (reg&3) + 8*(reg>>2) + 4*h.
  float gm[2][4];                       // [j][group within wave's 64-n window]
#pragma unroll
  for (int j = 0; j < 2; ++j) {
    const int lab = labLDS[wm + j * 32 + ml];
#pragma unroll
    for (int i = 0; i < 2; ++i) {
      int rel = lab - (n0 + wn + i * 32);
      if ((unsigned)rel < 32u && (((rel >> 2) & 1) == h)) {
        int r4 = rel & ~4;                        // remove the 4h bit (h matched)
        int reg = (r4 & 3) | ((r4 >> 3) << 2);
        acc[i][j][reg] = -INFINITY;               // mask the positive column
      }
      // regs 0..7: n-offsets {0..3,8..11}+4h -> group 2i; regs 8..15 -> group 2i+1
      float g0 = fmaxf(fmaxf(fmaxf(acc[i][j][0], acc[i][j][1]), fmaxf(acc[i][j][2], acc[i][j][3])),
                       fmaxf(fmaxf(acc[i][j][4], acc[i][j][5]), fmaxf(acc[i][j][6], acc[i][j][7])));
      float g1 = fmaxf(fmaxf(fmaxf(acc[i][j][8], acc[i][j][9]), fmaxf(acc[i][j][10], acc[i][j][11])),
                       fmaxf(fmaxf(acc[i][j][12], acc[i][j][13]), fmaxf(acc[i][j][14], acc[i][j][15])));
      g0 = fmaxf(g0, __shfl_xor(g0, 32));         // partner lane covers n-offsets +4
      g1 = fmaxf(g1, __shfl_xor(g1, 32));
      gm[j][2 * i] = g0; gm[j][2 * i + 1] = g1;
    }
  }
  {
    const int j = h;                              // half-wave stores its j (lanes duplicate across h)
    float4 o = make_float4(gm[j][0], gm[j][1], gm[j][2], gm[j][3]);
    int m = m0 + wm + j * 32 + ml;
    *(float4*)(cand + (size_t)m * (NTILES * 8) + bxTile * 8 + (wn >> 4)) = o;
  }
}

// fp16-bit monotone key <-> value
__device__ __forceinline__ float dec_key(int k) {
  if (k < 0x0400) return -INFINITY;
  ushort h = (k >= 0x8000) ? (ushort)(k ^ 0x8000) : (ushort)(~k & 0xFFFF);
  __half_raw hr; hr.x = h;
  return __half2float((__half)hr);
}

// ---------------- per-row: top-50 of 4096 pool values via key bisection + loss ----------------
__global__ void final_select(const float* __restrict__ cand, const float* __restrict__ f,
                             const float* __restrict__ cen, const int* __restrict__ label,
                             float* __restrict__ rowloss) {
  __shared__ float sred[8];
  __shared__ int   sint[8];
  const int row = blockIdx.x, tid = threadIdx.x;
  const int lane = tid & 63, wid = tid >> 6;
  const int lab = label[row];

  float v[16];
  const float4* p = (const float4*)(cand + (size_t)row * (NTILES * 8));
#pragma unroll
  for (int g = 0; g < 4; ++g) {
    float4 u = p[tid + g * 256];
    v[g * 4 + 0] = u.x; v[g * 4 + 1] = u.y; v[g * 4 + 2] = u.z; v[g * 4 + 3] = u.w;
  }
  float pv = f[(size_t)row * D_DIM + tid] * cen[(size_t)lab * D_DIM + tid];
  float m = -INFINITY;
#pragma unroll
  for (int k = 0; k < 16; ++k) m = fmaxf(m, v[k]);
#pragma unroll
  for (int o = 32; o > 0; o >>= 1) {
    m = fmaxf(m, __shfl_down(m, o));
    pv += __shfl_down(pv, o);
  }
  if (lane == 0) { sred[wid] = m; sred[4 + wid] = pv; }
  __syncthreads();
  m = fmaxf(fmaxf(sred[0], sred[1]), fmaxf(sred[2], sred[3]));
  const float pos = sred[4] + sred[5] + sred[6] + sred[7];

  // bisection seeded at the row max key
  __half hm = __float2half(m);
  int hb = (int)(*(ushort*)&hm);
  int km = (m >= 0.f) ? (0x8000 | hb) : (~hb & 0xFFFF);
  int lo = km - 2048, hi = km;
  if (lo < 0x0400) lo = 0x0400;
#pragma unroll
  for (int it = 0; it < 12; ++it) {
    int mid = (lo + hi) >> 1;
    float tau = dec_key(mid);
    int c = 0;
#pragma unroll
    for (int k = 0; k < 16; ++k) c += (v[k] > tau) ? 1 : 0;
#pragma unroll
    for (int o = 32; o > 0; o >>= 1) c += __shfl_down(c, o);
    if (lane == 0) sint[(it & 1) * 4 + wid] = c;
    __syncthreads();
    int base = (it & 1) * 4;
    int tot = sint[base] + sint[base + 1] + sint[base + 2] + sint[base + 3];
    if (tot <= 49) hi = mid; else lo = mid + 1;
  }

  const float tau = dec_key(hi);
  float sum = 0.f, se = 0.f; int c = 0;
#pragma unroll
  for (int k = 0; k < 16; ++k) {
    if (v[k] > tau) { ++c; sum += v[k]; se += expf(v[k] - m); }
  }
#pragma unroll
  for (int o = 32; o > 0; o >>= 1) {
    sum += __shfl_down(sum, o);
    se  += __shfl_down(se, o);
    c   += __shfl_down(c, o);
  }
  if (lane == 0) { sred[wid] = sum; sred[4 + wid] = se; sint[wid] = c; }
  __syncthreads();
  if (tid == 0) {
    float S = sred[0] + sred[1] + sred[2] + sred[3];
    float E = sred[4] + sred[5] + sred[6] + sred[7];
    int   C = sint[0] + sint[1] + sint[2] + sint[3];
    float nfill = (float)(N_NEG - C);
    S += nfill * tau;
    E += nfill * expf(tau - m);
    float M = fmaxf(m, pos);
    float seAll = E * expf(m - M) + expf(pos - M);
    float lse = M + logf(seAll);
    rowloss[row] = 0.9102f * lse - 0.9002f * pos - 2.0e-4f * S;
  }
}

__global__ void sum_loss(const float* __restrict__ rowloss, float* __restrict__ out) {
  __shared__ float red[4];
  const int tid = threadIdx.x;
  float s = 0.f;
  for (int i = tid; i < B_ROWS; i += 256) s += rowloss[i];
#pragma unroll
  for (int o = 32; o > 0; o >>= 1) s += __shfl_down(s, o);
  if ((tid & 63) == 0) red[tid >> 6] = s;
  __syncthreads();
  if (tid == 0) out[0] = (red[0] + red[1] + red[2] + red[3]) * (1.0f / B_ROWS);
}

extern "C" void kernel_launch(void* const* d_in, const int* in_sizes, int n_in,
                              void* d_out, int out_size, void* d_ws, size_t ws_size,
                              hipStream_t stream) {
  const float* f   = (const float*)d_in[0];
  const float* cen = (const float*)d_in[1];
  const int*   label = (const int*)d_in[2];
  float* out = (float*)d_out;

  char* ws = (char*)d_ws;
  float*  cand    = (float*)ws;                       // 32 MiB: [2048][512][8]
  ushort* fb      = (ushort*)(ws + 33554432);         // 1 MiB
  float*  rowloss = (float*)(ws + 34611200);          // 8 KiB
  ushort* cb      = (ushort*)(ws + 34619392);         // 32 MiB (fast path)
  const bool pre = ws_size >= (34619392ull + 33554432ull);

  cvt_both<<<(B_ROWS + C_COLS) / 8, 256, 0, stream>>>(f, cen, fb, cb, pre ? 1 : 0);

  dim3 grid(B_ROWS / 128, NTILES);  // (16 slabs, 512 tiles)
  if (pre) {
    gemm_reduce<true><<<grid, 256, 0, stream>>>(fb, cb, cen, label, cand);
  } else {
    gemm_reduce<false><<<grid, 256, 0, stream>>>(fb, nullptr, cen, label, cand);
  }

  final_select<<<B_ROWS, 256, 0, stream>>>(cand, f, cen, label, rowloss);
  sum_loss<<<1, 256, 0, stream>>>(rowloss, out);
}